// Round 4
// baseline (127.114 us; speedup 1.0000x reference)
//
#include <hip/hip_runtime.h>
#include <hip/hip_bf16.h>
#include <stdint.h>

#define BN_EPS 1e-3f

typedef __bf16 bf16x8 __attribute__((ext_vector_type(8)));
typedef float  f32x16 __attribute__((ext_vector_type(16)));

// Dims: B=256, F=64, Df=H=D=256, E=8. Tokens=16384; tile = 64 tokens (1 batch row).
// Grid 512 = 256 tiles x 2 expert-halves (eh); eh parity == XCD parity.
// LDS per WG: xb 32K + hb 32K + wrts 2K = 66K -> 2 WGs/CU (16 waves/CU).
// ws: [0,3.0M) pk (route partials overlay here, dead before pack) | fold 32KB | wrt 2KB | wb 64KB
static constexpr size_t WS_FOLD_OFF = 24ull * 131072ull;
static constexpr size_t WS_WRT_OFF  = WS_FOLD_OFF + 32768ull;
static constexpr size_t WS_WB_OFF   = WS_WRT_OFF + 2048ull;

// Unified swizzled LDS addr: frag-row fr (0..31, 8 k each), token tok (0..63), 16B units.
// XOR spreads banks: writers hit 32 distinct windows, readers stay contiguous-permuted.
#define XADDR(fr, tok) (((fr) << 10) + ((((tok) ^ (fr))) << 4))

// ---------------- BN fold ----------------
__global__ __launch_bounds__(256) void fold_kernel(
    const float* __restrict__ b1, const float* __restrict__ g1, const float* __restrict__ be1,
    const float* __restrict__ m1, const float* __restrict__ v1,
    const float* __restrict__ b2, const float* __restrict__ g2, const float* __restrict__ be2,
    const float* __restrict__ m2, const float* __restrict__ v2,
    float* __restrict__ fold) {
  int i = blockIdx.x * 256 + threadIdx.x;
  if (i < 2048) {
    float s1 = g1[i] * rsqrtf(v1[i] + BN_EPS);
    fold[i]        = s1;
    fold[2048 + i] = (b1[i] - m1[i]) * s1 + be1[i];
    float s2 = g2[i] * rsqrtf(v2[i] + BN_EPS);
    fold[4096 + i] = s2;
    fold[6144 + i] = (b2[i] - m2[i]) * s2 + be2[i];
  }
}

// ---------------- Weight pack: fp32 [E][K][N] -> bf16 MFMA-frag order ----------------
__global__ __launch_bounds__(256) void pack_kernel(
    const float* __restrict__ W1, const float* __restrict__ W2, const float* __restrict__ Wo,
    __bf16* __restrict__ pk) {
  __shared__ float sl[16 * 256];
  int bid = blockIdx.x;             // 384 = 24 mats * 16 ks
  int m = bid >> 4, ks = bid & 15;
  int L = m >> 3, e = m & 7;
  const float* Ws = (L == 0 ? W1 : (L == 1 ? W2 : Wo)) + (size_t)e * 65536 + (size_t)ks * 16 * 256;
  int t = threadIdx.x;
#pragma unroll
  for (int it = 0; it < 4; ++it) {
    int el4 = it * 256 + t;
    float4 v = *reinterpret_cast<const float4*>(Ws + (size_t)el4 * 4);
    *reinterpret_cast<float4*>(&sl[el4 * 4]) = v;
  }
  __syncthreads();
#pragma unroll
  for (int it = 0; it < 2; ++it) {
    int task = it * 256 + t;        // nb(8) x lane(64)
    int nb = task >> 6, l = task & 63;
    int colb = nb * 32 + (l & 31);
    int krow = (l >> 5) * 8;
    union { __bf16 h[8]; int4 v; } u;
#pragma unroll
    for (int i = 0; i < 8; ++i) u.h[i] = (__bf16)sl[(krow + i) * 256 + colb];
    size_t off = ((size_t)(m * 8 + nb) * 16 + ks) * 512 + (size_t)l * 8;
    *reinterpret_cast<int4*>(pk + off) = u.v;
  }
}

// ---------------- Routing pass 1: batch-partial sums (full-BW x read) ----------------
__global__ __launch_bounds__(256) void route1_kernel(
    const float* __restrict__ x, float* __restrict__ part) {
  int f = blockIdx.x, bq = blockIdx.y, t = threadIdx.x;   // 64 x 8 WGs
  const float* xp = x + (size_t)(bq * 32) * 16384 + f * 256 + t;
  float s = 0.f;
#pragma unroll 4
  for (int bi = 0; bi < 32; ++bi) s += xp[(size_t)bi * 16384];
  part[(size_t)(bq * 64 + f) * 256 + t] = s;
}

// ---------------- Routing pass 2: reduce + softmax + wb ----------------
__global__ __launch_bounds__(256) void route2_kernel(
    const float* __restrict__ part, const float* __restrict__ Wr, const float* __restrict__ br,
    const float* __restrict__ bo, float* __restrict__ wrt, float* __restrict__ wb) {
  __shared__ float feat[256];
  __shared__ float lg[8];
  __shared__ float wsm[8];
  int f = blockIdx.x, t = threadIdx.x;
  float a = 0.f;
#pragma unroll
  for (int bq = 0; bq < 8; ++bq) a += part[(size_t)(bq * 64 + f) * 256 + t];
  feat[t] = a * (1.0f / 256.0f);
  __syncthreads();
  if (t < 8) {
    float s = br[t];
    for (int d = 0; d < 256; ++d) s += feat[d] * Wr[d * 8 + t];
    lg[t] = s;
  }
  __syncthreads();
  if (t == 0) {
    float mx = lg[0];
#pragma unroll
    for (int e = 1; e < 8; ++e) mx = fmaxf(mx, lg[e]);
    float ex[8]; float sum = 0.f;
#pragma unroll
    for (int e = 0; e < 8; ++e) { ex[e] = expf(lg[e] - mx); sum += ex[e]; }
    float inv = 1.0f / sum;
#pragma unroll
    for (int e = 0; e < 8; ++e) { float v = ex[e] * inv; wsm[e] = v; wrt[f * 8 + e] = v; }
  }
  __syncthreads();
  float o = 0.f;
#pragma unroll
  for (int e = 0; e < 8; ++e) o += wsm[e] * bo[e * 256 + t];
  wb[f * 256 + t] = o;
}

// ---------------- Main fused MoE ----------------
// 512 thr = 8 waves; wave w owns 32 output cols (nb=w), all 64 tokens (2 mt tiles).
// SWAP=1 (L0/L1): acc = mfma(Wfrag, actfrag) -> C rows = h-cols, cols = tokens.
__device__ __forceinline__ void sweep(
    const char* __restrict__ src, const __bf16* __restrict__ pb,
    int l, int l31, int hi, int swap, f32x16 acc[2]) {
#pragma unroll
  for (int mt = 0; mt < 2; ++mt)
#pragma unroll
    for (int r = 0; r < 16; ++r) acc[mt][r] = 0.f;
  bf16x8 bq = *reinterpret_cast<const bf16x8*>(pb + (size_t)l * 8);
#pragma unroll
  for (int ks = 0; ks < 16; ++ks) {
    bf16x8 bn = (ks < 15) ? *reinterpret_cast<const bf16x8*>(pb + (size_t)(ks + 1) * 512 + (size_t)l * 8) : bq;
    int fr = 2 * ks + hi;
    bf16x8 a0 = *reinterpret_cast<const bf16x8*>(src + XADDR(fr, l31));
    bf16x8 a1 = *reinterpret_cast<const bf16x8*>(src + XADDR(fr, 32 + l31));
    if (swap) {
      acc[0] = __builtin_amdgcn_mfma_f32_32x32x16_bf16(bq, a0, acc[0], 0, 0, 0);
      acc[1] = __builtin_amdgcn_mfma_f32_32x32x16_bf16(bq, a1, acc[1], 0, 0, 0);
    } else {
      acc[0] = __builtin_amdgcn_mfma_f32_32x32x16_bf16(a0, bq, acc[0], 0, 0, 0);
      acc[1] = __builtin_amdgcn_mfma_f32_32x32x16_bf16(a1, bq, acc[1], 0, 0, 0);
    }
    bq = bn;
  }
}

__device__ __forceinline__ void epi_store(
    const f32x16 acc[2], const float* __restrict__ sA, const float* __restrict__ cA,
    char* __restrict__ dst, int l31, int hi, int w) {
#pragma unroll
  for (int g = 0; g < 4; ++g) {
    float4 s4 = *reinterpret_cast<const float4*>(sA + 8 * g);
    float4 c4 = *reinterpret_cast<const float4*>(cA + 8 * g);
    int fr = w * 4 + g;
#pragma unroll
    for (int mt = 0; mt < 2; ++mt) {
      union { __bf16 h[4]; uint2 u; } p;
#pragma unroll
      for (int j = 0; j < 4; ++j) {
        float sj = (&s4.x)[j], cj = (&c4.x)[j];
        p.h[j] = (__bf16)fmaxf(acc[mt][4 * g + j] * sj + cj, 0.f);
      }
      *reinterpret_cast<uint2*>(dst + XADDR(fr, mt * 32 + l31) + hi * 8) = p.u;
    }
  }
}

__global__ __launch_bounds__(512, 4) void moe_kernel(
    const float* __restrict__ x, const __bf16* __restrict__ pk,
    const float* __restrict__ fold, const float* __restrict__ wrt,
    const float* __restrict__ wb, float* __restrict__ out) {
  __shared__ char xb[32768];
  __shared__ char hb[32768];
  __shared__ float wrts[512];
  const int tid = threadIdx.x;
  const int l = tid & 63, w = tid >> 6;
  const int l31 = l & 31, hi = l >> 5;
  const int bid = blockIdx.x;
  const int tile = bid >> 1, eh = bid & 1;

  // ---- stage x -> bf16 LDS (swizzled, conflict-free both sides) ----
  {
    const float* xg = x + (size_t)tile * 16384;
#pragma unroll
    for (int i = 0; i < 4; ++i) {
      int u = i * 512 + tid;           // 2048 16B-units: tok(64) x k8(32)
      int tok = u >> 5, k8 = u & 31;
      const float* src = xg + (size_t)tok * 256 + k8 * 8;
      float4 v0 = *reinterpret_cast<const float4*>(src);
      float4 v1 = *reinterpret_cast<const float4*>(src + 4);
      union { __bf16 h[8]; int4 v; } p;
      p.h[0] = (__bf16)v0.x; p.h[1] = (__bf16)v0.y; p.h[2] = (__bf16)v0.z; p.h[3] = (__bf16)v0.w;
      p.h[4] = (__bf16)v1.x; p.h[5] = (__bf16)v1.y; p.h[6] = (__bf16)v1.z; p.h[7] = (__bf16)v1.w;
      *reinterpret_cast<int4*>(xb + XADDR(k8, tok)) = p.v;
    }
  }
  wrts[tid] = wrt[tid];   // 512 = 64 f x 8 e

  f32x16 outacc[2];
#pragma unroll
  for (int mt = 0; mt < 2; ++mt)
#pragma unroll
    for (int r = 0; r < 16; ++r) outacc[mt][r] = 0.f;

  __syncthreads();

  f32x16 acc[2];
#pragma unroll 1
  for (int ep = 0; ep < 4; ++ep) {
    const int e = eh * 4 + ep;
    // L0: read xb -> acc
    sweep(xb, pk + (size_t)((0 * 8 + e) * 8 + w) * 8192, l, l31, hi, 1, acc);
    __syncthreads();   // prev L2 done reading hb
    epi_store(acc, fold + 0 * 4096 + e * 256 + w * 32 + 4 * hi,
              fold + 0 * 4096 + 2048 + e * 256 + w * 32 + 4 * hi, hb, l31, hi, w);
    __syncthreads();   // hb visible
    // L1: read hb -> acc (in-place: barrier between read & write)
    sweep(hb, pk + (size_t)((1 * 8 + e) * 8 + w) * 8192, l, l31, hi, 1, acc);
    __syncthreads();   // all reads done
    epi_store(acc, fold + 1 * 4096 + e * 256 + w * 32 + 4 * hi,
              fold + 1 * 4096 + 2048 + e * 256 + w * 32 + 4 * hi, hb, l31, hi, w);
    __syncthreads();   // hb visible
    // L2 (normal): y = h @ Wo; weighted accumulate (regs only, no barrier)
    sweep(hb, pk + (size_t)((2 * 8 + e) * 8 + w) * 8192, l, l31, hi, 0, acc);
#pragma unroll
    for (int mt = 0; mt < 2; ++mt) {
#pragma unroll
      for (int r = 0; r < 16; ++r) {
        int row = mt * 32 + 4 * hi + (r & 3) + 8 * (r >> 2);
        outacc[mt][r] += wrts[row * 8 + e] * acc[mt][r];
      }
    }
  }

  // ---- combine: 2 commutative fp32 atomics per element (deterministic) ----
  float* og = out + (size_t)tile * 16384;
  const int col = w * 32 + l31;
#pragma unroll
  for (int mt = 0; mt < 2; ++mt) {
#pragma unroll
    for (int r = 0; r < 16; ++r) {
      int row = mt * 32 + 4 * hi + (r & 3) + 8 * (r >> 2);
      float v = outacc[mt][r];
      if (eh == 0) v += wb[row * 256 + col];
      unsafeAtomicAdd(og + row * 256 + col, v);
    }
  }
}

extern "C" void kernel_launch(void* const* d_in, const int* in_sizes, int n_in,
                              void* d_out, int out_size, void* d_ws, size_t ws_size,
                              hipStream_t stream) {
  const float* x   = (const float*)d_in[0];
  const float* Wr  = (const float*)d_in[1];
  const float* br  = (const float*)d_in[2];
  const float* W1  = (const float*)d_in[3];
  const float* b1  = (const float*)d_in[4];
  const float* g1  = (const float*)d_in[5];
  const float* be1 = (const float*)d_in[6];
  const float* m1  = (const float*)d_in[7];
  const float* v1  = (const float*)d_in[8];
  const float* W2  = (const float*)d_in[9];
  const float* b2  = (const float*)d_in[10];
  const float* g2  = (const float*)d_in[11];
  const float* be2 = (const float*)d_in[12];
  const float* m2  = (const float*)d_in[13];
  const float* v2  = (const float*)d_in[14];
  const float* Wo  = (const float*)d_in[15];
  const float* bo  = (const float*)d_in[16];
  float* out = (float*)d_out;

  __bf16* pk  = (__bf16*)d_ws;
  float* part = (float*)d_ws;                          // overlays pk; dead before pack
  float* fold = (float*)((char*)d_ws + WS_FOLD_OFF);
  float* wrt  = (float*)((char*)d_ws + WS_WRT_OFF);
  float* wb   = (float*)((char*)d_ws + WS_WB_OFF);

  hipMemsetAsync(out, 0, (size_t)out_size * sizeof(float), stream);
  hipLaunchKernelGGL(route1_kernel, dim3(64, 8), dim3(256), 0, stream, x, part);
  hipLaunchKernelGGL(route2_kernel, dim3(64), dim3(256), 0, stream, part, Wr, br, bo, wrt, wb);
  hipLaunchKernelGGL(fold_kernel, dim3(8), dim3(256), 0, stream,
                     b1, g1, be1, m1, v1, b2, g2, be2, m2, v2, fold);
  hipLaunchKernelGGL(pack_kernel, dim3(384), dim3(256), 0, stream, W1, W2, Wo, pk);
  hipLaunchKernelGGL(moe_kernel, dim3(512), dim3(512), 0, stream, x, pk, fold, wrt, wb, out);
}

// Round 5
// 123.824 us; speedup vs baseline: 1.0266x; 1.0266x over previous
//
#include <hip/hip_runtime.h>
#include <hip/hip_bf16.h>
#include <stdint.h>

#define BN_EPS 1e-3f

typedef __bf16 bf16x8 __attribute__((ext_vector_type(8)));
typedef float  f32x16 __attribute__((ext_vector_type(16)));

// Dims: B=256, F=64, Df=H=D=256, E=8. Tokens=16384; tile = 64 tokens (1 batch row).
// Grid 512 = 256 tiles x 2 expert-halves (eh); eh parity == XCD parity.
// LDS per WG: xb 32K + hb 32K + wrts 2K = 66K -> 2 WGs/CU (16 waves/CU).
// Routing weights are folded into the L1 epilogue (h *= wrt), so the L2 GEMM
// accumulates the weighted expert sum directly -> only ONE f32x16[2] accumulator.
// ws: [0,3.0M) pk (route partials overlay, dead before pack) | fold 32KB | wrt 2KB | wb 64KB
static constexpr size_t WS_FOLD_OFF = 24ull * 131072ull;
static constexpr size_t WS_WRT_OFF  = WS_FOLD_OFF + 32768ull;
static constexpr size_t WS_WB_OFF   = WS_WRT_OFF + 2048ull;

// Swizzled LDS addr: frag-row fr (0..31 = k/8), token tok (0..63), 16B units.
#define XADDR(fr, tok) (((fr) << 10) + ((((tok) ^ (fr))) << 4))

// ---------------- BN fold ----------------
__global__ __launch_bounds__(256) void fold_kernel(
    const float* __restrict__ b1, const float* __restrict__ g1, const float* __restrict__ be1,
    const float* __restrict__ m1, const float* __restrict__ v1,
    const float* __restrict__ b2, const float* __restrict__ g2, const float* __restrict__ be2,
    const float* __restrict__ m2, const float* __restrict__ v2,
    float* __restrict__ fold) {
  int i = blockIdx.x * 256 + threadIdx.x;
  if (i < 2048) {
    float s1 = g1[i] * rsqrtf(v1[i] + BN_EPS);
    fold[i]        = s1;
    fold[2048 + i] = (b1[i] - m1[i]) * s1 + be1[i];
    float s2 = g2[i] * rsqrtf(v2[i] + BN_EPS);
    fold[4096 + i] = s2;
    fold[6144 + i] = (b2[i] - m2[i]) * s2 + be2[i];
  }
}

// ---------------- Weight pack: fp32 [E][K][N] -> bf16 MFMA-frag order ----------------
__global__ __launch_bounds__(256) void pack_kernel(
    const float* __restrict__ W1, const float* __restrict__ W2, const float* __restrict__ Wo,
    __bf16* __restrict__ pk) {
  __shared__ float sl[16 * 256];
  int bid = blockIdx.x;             // 384 = 24 mats * 16 ks
  int m = bid >> 4, ks = bid & 15;
  int L = m >> 3, e = m & 7;
  const float* Ws = (L == 0 ? W1 : (L == 1 ? W2 : Wo)) + (size_t)e * 65536 + (size_t)ks * 16 * 256;
  int t = threadIdx.x;
#pragma unroll
  for (int it = 0; it < 4; ++it) {
    int el4 = it * 256 + t;
    float4 v = *reinterpret_cast<const float4*>(Ws + (size_t)el4 * 4);
    *reinterpret_cast<float4*>(&sl[el4 * 4]) = v;
  }
  __syncthreads();
#pragma unroll
  for (int it = 0; it < 2; ++it) {
    int task = it * 256 + t;        // nb(8) x lane(64)
    int nb = task >> 6, l = task & 63;
    int colb = nb * 32 + (l & 31);
    int krow = (l >> 5) * 8;
    union { __bf16 h[8]; int4 v; } u;
#pragma unroll
    for (int i = 0; i < 8; ++i) u.h[i] = (__bf16)sl[(krow + i) * 256 + colb];
    size_t off = ((size_t)(m * 8 + nb) * 16 + ks) * 512 + (size_t)l * 8;
    *reinterpret_cast<int4*>(pk + off) = u.v;
  }
}

// ---------------- Routing pass 1: batch-partial sums ----------------
__global__ __launch_bounds__(256) void route1_kernel(
    const float* __restrict__ x, float* __restrict__ part) {
  int f = blockIdx.x, bq = blockIdx.y, t = threadIdx.x;   // 64 x 8 WGs
  const float* xp = x + (size_t)(bq * 32) * 16384 + f * 256 + t;
  float s = 0.f;
#pragma unroll 4
  for (int bi = 0; bi < 32; ++bi) s += xp[(size_t)bi * 16384];
  part[(size_t)(bq * 64 + f) * 256 + t] = s;
}

// ---------------- Routing pass 2: reduce + softmax + wb ----------------
__global__ __launch_bounds__(256) void route2_kernel(
    const float* __restrict__ part, const float* __restrict__ Wr, const float* __restrict__ br,
    const float* __restrict__ bo, float* __restrict__ wrt, float* __restrict__ wb) {
  __shared__ float feat[256];
  __shared__ float lg[8];
  __shared__ float wsm[8];
  int f = blockIdx.x, t = threadIdx.x;
  float a = 0.f;
#pragma unroll
  for (int bq = 0; bq < 8; ++bq) a += part[(size_t)(bq * 64 + f) * 256 + t];
  feat[t] = a * (1.0f / 256.0f);
  __syncthreads();
  if (t < 8) {
    float s = br[t];
    for (int d = 0; d < 256; ++d) s += feat[d] * Wr[d * 8 + t];
    lg[t] = s;
  }
  __syncthreads();
  if (t == 0) {
    float mx = lg[0];
#pragma unroll
    for (int e = 1; e < 8; ++e) mx = fmaxf(mx, lg[e]);
    float ex[8]; float sum = 0.f;
#pragma unroll
    for (int e = 0; e < 8; ++e) { ex[e] = expf(lg[e] - mx); sum += ex[e]; }
    float inv = 1.0f / sum;
#pragma unroll
    for (int e = 0; e < 8; ++e) { float v = ex[e] * inv; wsm[e] = v; wrt[f * 8 + e] = v; }
  }
  __syncthreads();
  float o = 0.f;
#pragma unroll
  for (int e = 0; e < 8; ++e) o += wsm[e] * bo[e * 256 + t];
  wb[f * 256 + t] = o;
}

// ---------------- Main fused MoE ----------------
// 512 thr = 8 waves; wave w owns 32 output cols (nb=w), all 64 tokens (2 mt tiles).
// SWAP=1 (L0/L1): acc = mfma(Wfrag, actfrag) -> C rows = h-cols, cols = tokens.
// ZERO=0 (L2): accumulate into caller's acc across experts.
__device__ __forceinline__ void sweep(
    const char* __restrict__ src, const __bf16* __restrict__ pb,
    int l, int l31, int hi, int swap, int zero, f32x16 acc[2]) {
  if (zero) {
#pragma unroll
    for (int mt = 0; mt < 2; ++mt)
#pragma unroll
      for (int r = 0; r < 16; ++r) acc[mt][r] = 0.f;
  }
  // depth-2 B prefetch
  bf16x8 b0 = *reinterpret_cast<const bf16x8*>(pb + (size_t)l * 8);
  bf16x8 b1 = *reinterpret_cast<const bf16x8*>(pb + 512 + (size_t)l * 8);
#pragma unroll
  for (int ks = 0; ks < 16; ++ks) {
    bf16x8 bn = (ks < 14) ? *reinterpret_cast<const bf16x8*>(pb + (size_t)(ks + 2) * 512 + (size_t)l * 8) : b0;
    int fr = 2 * ks + hi;
    bf16x8 a0 = *reinterpret_cast<const bf16x8*>(src + XADDR(fr, l31));
    bf16x8 a1 = *reinterpret_cast<const bf16x8*>(src + XADDR(fr, 32 + l31));
    if (swap) {
      acc[0] = __builtin_amdgcn_mfma_f32_32x32x16_bf16(b0, a0, acc[0], 0, 0, 0);
      acc[1] = __builtin_amdgcn_mfma_f32_32x32x16_bf16(b0, a1, acc[1], 0, 0, 0);
    } else {
      acc[0] = __builtin_amdgcn_mfma_f32_32x32x16_bf16(a0, b0, acc[0], 0, 0, 0);
      acc[1] = __builtin_amdgcn_mfma_f32_32x32x16_bf16(a1, b0, acc[1], 0, 0, 0);
    }
    b0 = b1; b1 = bn;
  }
}

// Epilogue for swapped phases: BN + relu (+ optional per-token wrt scale), pack, LDS store.
__device__ __forceinline__ void epi_store(
    const f32x16 acc[2], const float* __restrict__ sA, const float* __restrict__ cA,
    char* __restrict__ dst, int l31, int hi, int w, float w0, float w1) {
#pragma unroll
  for (int g = 0; g < 4; ++g) {
    float4 s4 = *reinterpret_cast<const float4*>(sA + 8 * g);
    float4 c4 = *reinterpret_cast<const float4*>(cA + 8 * g);
    int fr = w * 4 + g;
#pragma unroll
    for (int mt = 0; mt < 2; ++mt) {
      float wm = (mt == 0) ? w0 : w1;
      union { __bf16 h[4]; uint2 u; } p;
#pragma unroll
      for (int j = 0; j < 4; ++j) {
        float sj = (&s4.x)[j], cj = (&c4.x)[j];
        p.h[j] = (__bf16)(wm * fmaxf(acc[mt][4 * g + j] * sj + cj, 0.f));
      }
      *reinterpret_cast<uint2*>(dst + XADDR(fr, mt * 32 + l31) + hi * 8) = p.u;
    }
  }
}

__global__ __launch_bounds__(512, 4) void moe_kernel(
    const float* __restrict__ x, const __bf16* __restrict__ pk,
    const float* __restrict__ fold, const float* __restrict__ wrt,
    const float* __restrict__ wb, float* __restrict__ out) {
  __shared__ char xb[32768];
  __shared__ char hb[32768];
  __shared__ float wrts[512];
  const int tid = threadIdx.x;
  const int l = tid & 63, w = tid >> 6;
  const int l31 = l & 31, hi = l >> 5;
  const int bid = blockIdx.x;
  const int tile = bid >> 1, eh = bid & 1;

  // ---- stage x -> bf16 LDS (swizzled) ----
  {
    const float* xg = x + (size_t)tile * 16384;
#pragma unroll
    for (int i = 0; i < 4; ++i) {
      int u = i * 512 + tid;           // 2048 16B-units: tok(64) x k8(32)
      int tok = u >> 5, k8 = u & 31;
      const float* src = xg + (size_t)tok * 256 + k8 * 8;
      float4 v0 = *reinterpret_cast<const float4*>(src);
      float4 v1 = *reinterpret_cast<const float4*>(src + 4);
      union { __bf16 h[8]; int4 v; } p;
      p.h[0] = (__bf16)v0.x; p.h[1] = (__bf16)v0.y; p.h[2] = (__bf16)v0.z; p.h[3] = (__bf16)v0.w;
      p.h[4] = (__bf16)v1.x; p.h[5] = (__bf16)v1.y; p.h[6] = (__bf16)v1.z; p.h[7] = (__bf16)v1.w;
      *reinterpret_cast<int4*>(xb + XADDR(k8, tok)) = p.v;
    }
  }
  wrts[tid] = wrt[tid];   // 512 = 64 f x 8 e

  f32x16 outacc[2];       // L2 accumulates weighted expert sum directly
#pragma unroll
  for (int mt = 0; mt < 2; ++mt)
#pragma unroll
    for (int r = 0; r < 16; ++r) outacc[mt][r] = 0.f;

  __syncthreads();

  f32x16 acc[2];
#pragma unroll 1
  for (int ep = 0; ep < 4; ++ep) {
    const int e = eh * 4 + ep;
    // L0: read xb -> acc
    sweep(xb, pk + (size_t)((0 * 8 + e) * 8 + w) * 8192, l, l31, hi, 1, 1, acc);
    __syncthreads();   // prev L2 done reading hb
    epi_store(acc, fold + 0 * 4096 + e * 256 + w * 32 + 4 * hi,
              fold + 0 * 4096 + 2048 + e * 256 + w * 32 + 4 * hi, hb, l31, hi, w, 1.f, 1.f);
    __syncthreads();   // hb visible
    // L1: read hb -> acc (in-place; barrier separates read & write); fold wrt into h
    sweep(hb, pk + (size_t)((1 * 8 + e) * 8 + w) * 8192, l, l31, hi, 1, 1, acc);
    __syncthreads();   // all reads done
    {
      float w0 = wrts[l31 * 8 + e];
      float w1 = wrts[(32 + l31) * 8 + e];
      epi_store(acc, fold + 1 * 4096 + e * 256 + w * 32 + 4 * hi,
                fold + 1 * 4096 + 2048 + e * 256 + w * 32 + 4 * hi, hb, l31, hi, w, w0, w1);
    }
    __syncthreads();   // hb visible
    // L2 (normal): outacc += (wrt*h) @ Wo  (direct MFMA accumulate, no barrier)
    sweep(hb, pk + (size_t)((2 * 8 + e) * 8 + w) * 8192, l, l31, hi, 0, 0, outacc);
  }

  // ---- combine: 2 commutative fp32 atomics per element (deterministic) ----
  float* og = out + (size_t)tile * 16384;
  const int col = w * 32 + l31;
#pragma unroll
  for (int mt = 0; mt < 2; ++mt) {
#pragma unroll
    for (int r = 0; r < 16; ++r) {
      int row = mt * 32 + 4 * hi + (r & 3) + 8 * (r >> 2);
      float v = outacc[mt][r];
      if (eh == 0) v += wb[row * 256 + col];
      unsafeAtomicAdd(og + row * 256 + col, v);
    }
  }
}

extern "C" void kernel_launch(void* const* d_in, const int* in_sizes, int n_in,
                              void* d_out, int out_size, void* d_ws, size_t ws_size,
                              hipStream_t stream) {
  const float* x   = (const float*)d_in[0];
  const float* Wr  = (const float*)d_in[1];
  const float* br  = (const float*)d_in[2];
  const float* W1  = (const float*)d_in[3];
  const float* b1  = (const float*)d_in[4];
  const float* g1  = (const float*)d_in[5];
  const float* be1 = (const float*)d_in[6];
  const float* m1  = (const float*)d_in[7];
  const float* v1  = (const float*)d_in[8];
  const float* W2  = (const float*)d_in[9];
  const float* b2  = (const float*)d_in[10];
  const float* g2  = (const float*)d_in[11];
  const float* be2 = (const float*)d_in[12];
  const float* m2  = (const float*)d_in[13];
  const float* v2  = (const float*)d_in[14];
  const float* Wo  = (const float*)d_in[15];
  const float* bo  = (const float*)d_in[16];
  float* out = (float*)d_out;

  __bf16* pk  = (__bf16*)d_ws;
  float* part = (float*)d_ws;                          // overlays pk; dead before pack
  float* fold = (float*)((char*)d_ws + WS_FOLD_OFF);
  float* wrt  = (float*)((char*)d_ws + WS_WRT_OFF);
  float* wb   = (float*)((char*)d_ws + WS_WB_OFF);

  hipMemsetAsync(out, 0, (size_t)out_size * sizeof(float), stream);
  hipLaunchKernelGGL(route1_kernel, dim3(64, 8), dim3(256), 0, stream, x, part);
  hipLaunchKernelGGL(route2_kernel, dim3(64), dim3(256), 0, stream, part, Wr, br, bo, wrt, wb);
  hipLaunchKernelGGL(fold_kernel, dim3(8), dim3(256), 0, stream,
                     b1, g1, be1, m1, v1, b2, g2, be2, m2, v2, fold);
  hipLaunchKernelGGL(pack_kernel, dim3(384), dim3(256), 0, stream, W1, W2, Wo, pk);
  hipLaunchKernelGGL(moe_kernel, dim3(512), dim3(512), 0, stream, x, pk, fold, wrt, wb, out);
}